// Round 10
// baseline (396.204 us; speedup 1.0000x reference)
//
#include <hip/hip_runtime.h>
#include <hip/hip_bf16.h>
#include <math.h>

typedef __hip_bfloat16 bf16;
typedef short s16x8 __attribute__((ext_vector_type(8)));
typedef float f32x4 __attribute__((ext_vector_type(4)));

#define NQ 200
#define SEQ 8
#define DM 2048
#define OUTD 1152
#define LT 28
#define M_ALL 6300
#define SM 5600
#define SN_PAD 768
#define ATT_STRIDE 800   // 5 classes x 160 (16B-aligned class slots)
#define N2 2304          // W viewed as [2304, 2048]
#define KP 160
#define CH_Q 50
#define CH_ROWS 1400
#define CH_MPAD 1408

// direct global->LDS DMA, 16 B per lane, LDS dest = base + lane*16
#define GLOAD_LDS16(g, l)                                          \
    __builtin_amdgcn_global_load_lds(                              \
        (const __attribute__((address_space(1))) void*)(g),        \
        (__attribute__((address_space(3))) void*)(l), 16, 0, 0)

__device__ __forceinline__ float bf2f(bf16 v) { return __bfloat162float(v); }
__device__ __forceinline__ bf16 f2bf(float v) { return __float2bfloat16(v); }
__device__ __forceinline__ float ubits2f(unsigned int u16) {
    unsigned int i = u16 << 16;
    float f; __builtin_memcpy(&f, &i, 4); return f;
}
__device__ __forceinline__ unsigned short f2bits(float f) {
    bf16 b = __float2bfloat16(f);
    unsigned short u; __builtin_memcpy(&u, &b, 2); return u;
}

__device__ const int TUP_A[LT] = {0,0,0,0,0,0,0,1,1,1,1,1,1,2,2,2,2,2,3,3,3,3,4,4,4,5,5,6};
__device__ const int TUP_B[LT] = {1,2,3,4,5,6,7,2,3,4,5,6,7,3,4,5,6,7,4,5,6,7,5,6,7,6,7,7};

// ---------------------------------------------------------------------------
// prep: blocks [0,9216) convert [k_w|v_w] fp32->bf16; blocks [9216,11016)
// build pexb[r][d] = src[n][s][d] + pe[s][d]
// ---------------------------------------------------------------------------
__global__ __launch_bounds__(256) void prep_k(const float4* __restrict__ kw,
                                              const float4* __restrict__ vw,
                                              ushort4* __restrict__ wbf,
                                              const float* __restrict__ sup,
                                              const float* __restrict__ qry,
                                              bf16* __restrict__ pexb) {
    const int b = blockIdx.x, t = threadIdx.x;
    if (b < 9216) {
        int i = b * 256 + t;   // 0 .. 2,359,295
        float4 v = (i < 1179648) ? kw[i] : vw[i - 1179648];
        ushort4 r;
        r.x = f2bits(v.x); r.y = f2bits(v.y); r.z = f2bits(v.z); r.w = f2bits(v.w);
        wbf[i] = r;
        return;
    }
    int r = b - 9216;          // 0 .. 1799
    int n, s;
    const float* src;
    if (r < 200) { n = r >> 3; s = r & 7; src = sup; }
    else { int rr = r - 200; n = rr >> 3; s = rr & 7; src = qry; }
    const float* row = src + ((size_t)n * SEQ + s) * DM;
    bf16* orow = pexb + (size_t)r * DM;
    for (int d = t; d < DM; d += 256) {
        float dv = expf((float)(d & ~1) * (-9.210340371976184f / 2048.0f));
        float ang = (float)s * dv;
        float pe = (d & 1) ? cosf(ang) * 0.1f : sinf(ang) * 0.1f;
        orow[d] = f2bf(row[d] + pe);
    }
}

// ---------------------------------------------------------------------------
// MFMA bf16 GEMM with global_load_lds (width 16) staging.
// C = scale*A*B^T; z shifts A/B/C by aZ/bZ/cZ elements; rows >= mlim skipped.
// LDS k-quad-major: Xs[(kq*128 + row)*8 + (k&7)]. Staging: wave w DMAs
// k-quad w, rows {lane, 64+lane} (lane-linear LDS dest, wave-uniform base).
// Requires A/B base+lda 16B-aligned.
// ---------------------------------------------------------------------------
__global__ __launch_bounds__(256) void gemm_bt(
    const bf16* __restrict__ A, int lda, size_t aZ,
    const bf16* __restrict__ B, int ldb, size_t bZ,
    float scale, bf16* __restrict__ C, int ldc, size_t cZ, int K, int mlim) {
    const unsigned short* Ag0 = (const unsigned short*)A + aZ * blockIdx.z;
    const unsigned short* Bg0 = (const unsigned short*)B + bZ * blockIdx.z;
    const size_t cbase = cZ * blockIdx.z;
    const int tile_m = blockIdx.x * 128, tile_n = blockIdx.y * 128;
    __shared__ unsigned short As[4 * 128 * 8];
    __shared__ unsigned short Bs[4 * 128 * 8];
    const int t = threadIdx.x, lane = t & 63, wave = t >> 6;
    const int wm = (wave & 1) * 64, wn = (wave >> 1) * 64;

    const unsigned short* AgL0 = Ag0 + (size_t)(tile_m + lane) * lda + wave * 8;
    const unsigned short* AgL1 = Ag0 + (size_t)(tile_m + 64 + lane) * lda + wave * 8;
    const unsigned short* BgL0 = Bg0 + (size_t)(tile_n + lane) * ldb + wave * 8;
    const unsigned short* BgL1 = Bg0 + (size_t)(tile_n + 64 + lane) * ldb + wave * 8;
    unsigned short* AsD0 = &As[(wave * 128 + 0) * 8];
    unsigned short* AsD1 = &As[(wave * 128 + 64) * 8];
    unsigned short* BsD0 = &Bs[(wave * 128 + 0) * 8];
    unsigned short* BsD1 = &Bs[(wave * 128 + 64) * 8];

    const int fr = lane & 15, kq = lane >> 4;

    f32x4 acc[4][4];
#pragma unroll
    for (int i = 0; i < 4; i++)
#pragma unroll
        for (int j = 0; j < 4; j++) acc[i][j] = {0.f, 0.f, 0.f, 0.f};

    for (int k0 = 0; k0 < K; k0 += 32) {
        __syncthreads();   // previous iteration's fragment reads complete
        GLOAD_LDS16(AgL0 + k0, AsD0);
        GLOAD_LDS16(AgL1 + k0, AsD1);
        GLOAD_LDS16(BgL0 + k0, BsD0);
        GLOAD_LDS16(BgL1 + k0, BsD1);
        __syncthreads();   // drains vmcnt: LDS tiles ready
        s16x8 af[4], bfv[4];
#pragma unroll
        for (int i = 0; i < 4; i++)
            af[i] = *(const s16x8*)&As[(kq * 128 + wm + i * 16 + fr) * 8];
#pragma unroll
        for (int j = 0; j < 4; j++)
            bfv[j] = *(const s16x8*)&Bs[(kq * 128 + wn + j * 16 + fr) * 8];
#pragma unroll
        for (int i = 0; i < 4; i++)
#pragma unroll
            for (int j = 0; j < 4; j++)
                acc[i][j] = __builtin_amdgcn_mfma_f32_16x16x32_bf16(af[i], bfv[j], acc[i][j], 0, 0, 0);
    }

    const int rb = kq * 4;
#pragma unroll
    for (int i = 0; i < 4; i++)
#pragma unroll
        for (int j = 0; j < 4; j++) {
            const int col = tile_n + wn + j * 16 + fr;
#pragma unroll
            for (int r = 0; r < 4; r++) {
                const int row = tile_m + wm + i * 16 + rb + r;
                if (row < mlim)
                    C[cbase + (size_t)row * ldc + col] = f2bf(acc[i][j][r] * scale);
            }
        }
}

// ---------------------------------------------------------------------------
// combine_kv: ks[m] = LN(Yk[ra][2n]+Yk[rb][2n+1]+kb), vs[m] = Yv sum + vb
// ---------------------------------------------------------------------------
__global__ __launch_bounds__(256) void combine_kv(
    const unsigned int* __restrict__ Yk, const unsigned int* __restrict__ Yv,
    const float* __restrict__ kb, const float* __restrict__ vb,
    const float* __restrict__ lng, const float* __restrict__ lnb,
    bf16* __restrict__ ks, bf16* __restrict__ vs) {
    const int m = blockIdx.x, t = threadIdx.x, lane = t & 63, wave = t >> 6;
    int mm = m < 700 ? m : m - 700;
    int base = m < 700 ? 0 : 200;
    int nsamp = mm / LT, l = mm - nsamp * LT;
    const size_t ra = (size_t)(base + nsamp * 8 + TUP_A[l]) * (N2 / 2);
    const size_t rb = (size_t)(base + nsamp * 8 + TUP_B[l]) * (N2 / 2);
    const unsigned int* yka = Yk + ra;
    const unsigned int* ykb = Yk + rb;
    const unsigned int* yva = Yv + ra;
    const unsigned int* yvb = Yv + rb;
    float vals[5];
    int cnt = 0;
    float s = 0.f, s2 = 0.f;
    for (int n = t; n < OUTD; n += 256) {
        unsigned int ua = yka[n], ub = ykb[n];
        float vk = ubits2f(ua & 0xFFFFu) + ubits2f(ub >> 16) + kb[n];
        vals[cnt++] = vk;
        s += vk; s2 += vk * vk;
        unsigned int va = yva[n], vbu = yvb[n];
        vs[(size_t)m * OUTD + n] =
            f2bf(ubits2f(va & 0xFFFFu) + ubits2f(vbu >> 16) + vb[n]);
    }
    for (int o = 32; o > 0; o >>= 1) { s += __shfl_xor(s, o); s2 += __shfl_xor(s2, o); }
    __shared__ float r1[4], r2[4];
    if (lane == 0) { r1[wave] = s; r2[wave] = s2; }
    __syncthreads();
    s = r1[0] + r1[1] + r1[2] + r1[3];
    s2 = r2[0] + r2[1] + r2[2] + r2[3];
    float mu = s * (1.f / OUTD);
    float var = s2 * (1.f / OUTD) - mu * mu;
    float inv = rsqrtf(fmaxf(var, 0.f) + 1e-5f);
    cnt = 0;
    for (int n = t; n < OUTD; n += 256)
        ks[(size_t)m * OUTD + n] = f2bf((vals[cnt++] - mu) * inv * lng[n] + lnb[n]);
}

// ---------------------------------------------------------------------------
// softmax over 5 blocks of 140 support cols; class slot stride 160 in attn.
// Cols 140..159 of each slot are never zeroed: vsp's zero K-pad kills them.
// ---------------------------------------------------------------------------
__global__ __launch_bounds__(256) void softmax_k(const bf16* __restrict__ sc,
                                                 bf16* __restrict__ attn) {
    int row = blockIdx.x, t = threadIdx.x, lane = t & 63, wave = t >> 6;
    __shared__ float redm[4], reds[4];
    for (int w = 0; w < 5; w++) {
        float v = (t < 140) ? bf2f(sc[(size_t)row * SN_PAD + w * 140 + t]) : -3.0e38f;
        float m = v;
        for (int o = 32; o > 0; o >>= 1) m = fmaxf(m, __shfl_xor(m, o));
        if (lane == 0) redm[wave] = m;
        __syncthreads();
        m = fmaxf(fmaxf(redm[0], redm[1]), fmaxf(redm[2], redm[3]));
        float e = (t < 140) ? __expf(v - m) : 0.f;
        float s = e;
        for (int o = 32; o > 0; o >>= 1) s += __shfl_xor(s, o);
        if (lane == 0) reds[wave] = s;
        __syncthreads();
        s = reds[0] + reds[1] + reds[2] + reds[3];
        if (t < 140) attn[(size_t)row * ATT_STRIDE + w * 160 + t] = f2bf(e / s);
        __syncthreads();
    }
}

// ---------------------------------------------------------------------------
// vsp[w][d][j] = vs[w*140+j][d] (j>=140 -> 0); block 0 also zeroes gbuf
// ---------------------------------------------------------------------------
__global__ __launch_bounds__(256) void vspad_k(const bf16* __restrict__ vs,
                                               bf16* __restrict__ vp,
                                               float* __restrict__ gbuf) {
    int idx = blockIdx.x * 256 + threadIdx.x;
    if (blockIdx.x == 0)
        for (int i = threadIdx.x; i < NQ * 21; i += 256) gbuf[i] = 0.f;
    if (idx >= 5 * OUTD * KP) return;
    int j = idx % KP;
    int rest = idx / KP;
    int dcol = rest % OUTD;
    int w = rest / OUTD;
    vp[idx] = (j < 140) ? vs[(size_t)(w * 140 + j) * OUTD + dcol] : f2bf(0.f);
}

// ---------------------------------------------------------------------------
// Gram reduce over a proto chunk -> 21 sufficient stats per query
// ---------------------------------------------------------------------------
__global__ __launch_bounds__(256) void gramred_k(const bf16* __restrict__ protoc,
                                                 const bf16* __restrict__ vs,
                                                 float* __restrict__ gbuf,
                                                 int row0, int q0) {
    const int ql = blockIdx.x;
    const int lg = blockIdx.y;
    const int t = threadIdx.x, lane = t & 63, wave = t >> 6;
    const size_t PZ = (size_t)CH_MPAD * OUTD;
    float g[15] = {0.f};
    float h[5] = {0.f, 0.f, 0.f, 0.f, 0.f};
    float e = 0.f;
    for (int idx = t; idx < 4 * OUTD; idx += 256) {
        int l = lg * 4 + idx / OUTD;
        int d = idx - (idx / OUTD) * OUTD;
        size_t ml = (size_t)(ql * LT + l) * OUTD + d;
        float pv[5];
#pragma unroll
        for (int w = 0; w < 5; w++) pv[w] = bf2f(protoc[w * PZ + ml]);
        float v = bf2f(vs[(size_t)(700 + row0 + ql * LT + l) * OUTD + d]);
        e += v * v;
        int c = 0;
#pragma unroll
        for (int a = 0; a < 5; a++) {
            h[a] += v * pv[a];
#pragma unroll
            for (int b = a; b < 5; b++) g[c++] += pv[a] * pv[b];
        }
    }
    float vals[21];
#pragma unroll
    for (int k = 0; k < 15; k++) vals[k] = g[k];
#pragma unroll
    for (int k = 0; k < 5; k++) vals[15 + k] = h[k];
    vals[20] = e;
#pragma unroll
    for (int k = 0; k < 21; k++)
        for (int o = 32; o > 0; o >>= 1) vals[k] += __shfl_xor(vals[k], o);
    __shared__ float red[4][21];
    if (lane == 0)
#pragma unroll
        for (int k = 0; k < 21; k++) red[wave][k] = vals[k];
    __syncthreads();
    if (t < 21) {
        float s = red[0][t] + red[1][t] + red[2][t] + red[3][t];
        atomicAdd(&gbuf[(q0 + ql) * 21 + t], s);
    }
}

// ---------------------------------------------------------------------------
// out (fp32): per q -> 25 sim + 5 ori
// ---------------------------------------------------------------------------
__global__ __launch_bounds__(64) void out_k(const float* __restrict__ gbuf,
                                            float* __restrict__ out) {
    int q = blockIdx.x;
    if (threadIdx.x != 0) return;
    const float* r = gbuf + q * 21;
    float G[5][5];
    int c = 0;
    for (int a = 0; a < 5; a++)
        for (int b = a; b < 5; b++) { G[a][b] = r[c]; G[b][a] = r[c]; c++; }
    float e = r[20];
    float nrm[5];
    for (int a = 0; a < 5; a++) nrm[a] = sqrtf(fmaxf(G[a][a], 0.f));
    for (int a = 0; a < 5; a++)
        for (int b = 0; b < 5; b++)
            out[(size_t)q * 25 + a * 5 + b] = G[a][b] / fmaxf(nrm[a] * nrm[b], 1e-8f);
    for (int w = 0; w < 5; w++)
        out[5000 + (size_t)q * 5 + w] = -(e - 2.f * r[15 + w] + G[w][w]) * (1.f / 28.f);
}

// ---------------------------------------------------------------------------
extern "C" void kernel_launch(void* const* d_in, const int* in_sizes, int n_in,
                              void* d_out, int out_size, void* d_ws, size_t ws_size,
                              hipStream_t stream) {
    const float* sup = (const float*)d_in[0];
    // d_in[1] = support_labels int32 — unused (sorted equal-shot)
    const float* qry = (const float*)d_in[2];
    const float* k_w = (const float*)d_in[3];
    const float* k_b = (const float*)d_in[4];
    const float* v_w = (const float*)d_in[5];
    const float* v_b = (const float*)d_in[6];
    const float* lng = (const float*)d_in[7];
    const float* lnb = (const float*)d_in[8];
    (void)in_sizes; (void)n_in; (void)out_size; (void)ws_size;

    // layout (bytes), peak 50,257,312 (<= verified ws_size >= 54.5 MB):
    //   pexb   @0           7,864,320 (1920 rows; 1800 real)  dead after proj
    //   wbf    @7,864,320  18,874,368 (k|v bf16)              dead after proj
    //   Yk     @26,738,688  8,294,400 (1800x2304)             dead after comb
    //   Yv     @35,033,088  8,294,400                         dead after comb
    //   ks     @0          14,588,928 (6332 rows; 6300 real)  dead after scores
    //   vs     @16,220,160 14,515,200 (6300 rows)             live to end
    //   sc     @30,735,360  8,650,752 (over dead Yk/Yv)       dead after softmax
    //   vsp    @39,386,112  1,843,200
    //   attn   @41,229,312  9,011,200 (5632 rows x 800)
    //   gbuf   @50,240,512     16,800
    //   protoc @0          16,220,160 (over dead ks, after scores)
    char* ws = (char*)d_ws;
    bf16* pexb   = (bf16*)(ws + 0);
    bf16* wbf    = (bf16*)(ws + 7864320);
    bf16* Yk     = (bf16*)(ws + 26738688);
    bf16* Yv     = (bf16*)(ws + 35033088);
    bf16* ks     = (bf16*)(ws + 0);
    bf16* vs     = (bf16*)(ws + 16220160);
    bf16* sc     = (bf16*)(ws + 30735360);
    bf16* vsp    = (bf16*)(ws + 39386112);
    bf16* attn   = (bf16*)(ws + 41229312);
    float* gbuf  = (float*)(ws + 50240512);
    bf16* protoc = (bf16*)(ws + 0);

    prep_k<<<dim3(11016), dim3(256), 0, stream>>>(
        (const float4*)k_w, (const float4*)v_w, (ushort4*)wbf, sup, qry, pexb);

    // fused K+V projection: z in {k,v}; Y[1800,2304] = pexb @ W_view^T
    gemm_bt<<<dim3(15, 18, 2), dim3(256), 0, stream>>>(
        pexb, DM, 0, wbf, DM, (size_t)4718592,
        1.0f, Yk, N2, (size_t)4147200, DM, 1800);

    combine_kv<<<dim3(M_ALL), dim3(256), 0, stream>>>(
        (const unsigned int*)Yk, (const unsigned int*)Yv,
        k_b, v_b, lng, lnb, ks, vs);

    // scores: ks_q[5632,1152] @ ks_s[768,1152]^T / sqrt(1152)
    gemm_bt<<<dim3(44, 6, 1), dim3(256), 0, stream>>>(
        ks + (size_t)700 * OUTD, OUTD, 0, ks, OUTD, 0,
        0.029462782549439484f, sc, SN_PAD, 0, OUTD, 5600);

    vspad_k<<<dim3((5 * OUTD * KP + 255) / 256), dim3(256), 0, stream>>>(
        vs, vsp, gbuf);
    softmax_k<<<dim3(SM), dim3(256), 0, stream>>>(sc, attn);

    // proto chunks: 4 x 50 queries; per-class GEMM then Gram reduce
    for (int c = 0; c < 4; c++) {
        gemm_bt<<<dim3(11, 9, 5), dim3(256), 0, stream>>>(
            attn + (size_t)c * CH_ROWS * ATT_STRIDE, ATT_STRIDE, (size_t)160,
            vsp, KP, (size_t)OUTD * KP,
            1.0f, protoc, OUTD, (size_t)CH_MPAD * OUTD, KP, CH_ROWS);
        gramred_k<<<dim3(CH_Q, 7), dim3(256), 0, stream>>>(
            protoc, vs, gbuf, c * CH_ROWS, c * CH_Q);
    }

    out_k<<<dim3(NQ), dim3(64), 0, stream>>>(gbuf, (float*)d_out);
}